// Round 7
// baseline (2023.403 us; speedup 1.0000x reference)
//
#include <hip/hip_runtime.h>

#define TT 1024
#define BB 2048
#define EPSC 1e-4f
#define LDP 20   // padded LDS row stride (floats): max 2-way bank aliasing (free)
#define WPB 4    // independent waves per block

// Fully wave-independent fused Kalman filter. 2048 waves; each wave
// redundantly runs the batch-independent Riccati/gain chain (registers +
// private LDS scratch, wave-synchronous, NO s_barrier anywhere) and folds in
// the mean recurrence for its own batch inline: lane (r,q) holds
// A_t[r][4q..4q+3] (av) and G_t[r][0..3] (x0..x3) in registers at the end of
// each gains step. No inter-wave communication of any kind -> hang-proof,
// no vmcnt drains on the critical path.
__global__ __launch_bounds__(64 * WPB, 2)
void ssm_wave(const float* __restrict__ y, const float* __restrict__ F,
              const float* __restrict__ H, const float* __restrict__ Qc,
              const float* __restrict__ Rc, const float* __restrict__ im,
              const float* __restrict__ icc, float* __restrict__ out)
{
    __shared__ __align__(16) float m1s[WPB][16 * LDP];
    __shared__ __align__(16) float m2s[WPB][16 * LDP];

    const int tid = (int)threadIdx.x;
    const int w   = tid >> 6;
    const int l   = tid & 63;
    const int r   = l & 15;
    const int q   = l >> 4;
    const int b   = (int)blockIdx.x * WPB + w;

    float* M1 = m1s[w];
    float* M2 = m2s[w];

    // ---- loop-invariant operands in registers ----
    float Fq[4][16];   // F[4q+i][k]
    float Fr[16];      // F[r][k]
    float Frq[4];      // F[r][4q+i]
    float HFq[4][4];   // (H F)[m][4q+i]
    float Hn4q[4][4];  // H[n][4q+i]
    float Qq[4];       // Q[r][4q+i]
    float Rrow[4];     // R[q][n]
    float Hqr = H[q*16 + r];
    float prow[16];    // replicated full row r of symmetric P

    #pragma unroll
    for (int i = 0; i < 4; ++i)
        #pragma unroll
        for (int k = 0; k < 16; ++k) Fq[i][k] = F[(4*q + i)*16 + k];
    #pragma unroll
    for (int k = 0; k < 16; ++k) Fr[k] = F[r*16 + k];
    #pragma unroll
    for (int i = 0; i < 4; ++i) Frq[i] = F[r*16 + 4*q + i];
    #pragma unroll
    for (int n = 0; n < 4; ++n)
        #pragma unroll
        for (int i = 0; i < 4; ++i) Hn4q[n][i] = H[n*16 + 4*q + i];
    #pragma unroll
    for (int m = 0; m < 4; ++m)
        #pragma unroll
        for (int i = 0; i < 4; ++i) {
            float acc = 0.0f;
            #pragma unroll
            for (int k = 0; k < 16; ++k) acc += H[m*16 + k] * F[k*16 + 4*q + i];
            HFq[m][i] = acc;
        }
    #pragma unroll
    for (int i = 0; i < 4; ++i) {
        const int c = 4*q + i;
        float acc = (r == c) ? EPSC : 0.0f;
        #pragma unroll
        for (int k = 0; k < 16; ++k) acc += Qc[r*16 + k] * Qc[c*16 + k];
        Qq[i] = acc;
    }
    #pragma unroll
    for (int n = 0; n < 4; ++n) {
        float acc = (q == n) ? EPSC : 0.0f;
        #pragma unroll
        for (int k = 0; k < 4; ++k) acc += Rc[q*4 + k] * Rc[n*4 + k];
        Rrow[n] = acc;
    }
    #pragma unroll
    for (int k = 0; k < 16; ++k) {
        float acc = (r == k) ? EPSC : 0.0f;
        #pragma unroll
        for (int j = 0; j < 16; ++j) acc += icc[r*16 + j] * icc[k*16 + j];
        prow[k] = acc;   // P0 row r (exactly symmetric by construction)
    }

    // ---- means state: lane (r,q) holds mean[4q..4q+3], replicated over r ----
    float mq[4];
    #pragma unroll
    for (int i = 0; i < 4; ++i) mq[i] = im[4*q + i];
    const float4* Y4 = (const float4*)y + (size_t)b * TT;
    float* outb = out + (size_t)b * TT * 16;
    float4 yv = Y4[0];

    #pragma unroll 1
    for (int t = 0; t < TT; ++t) {
        // ---- C = P F^T : c[i] = sum_k prow[k] Fq[i][k] ----
        float c0 = 0.f, c1 = 0.f, c2 = 0.f, c3 = 0.f;
        #pragma unroll
        for (int k = 0; k < 16; ++k) {
            c0 += prow[k]*Fq[0][k]; c1 += prow[k]*Fq[1][k];
            c2 += prow[k]*Fq[2][k]; c3 += prow[k]*Fq[3][k];
        }
        // ---- RT_A: transpose C through LDS; cov_p = F C + Q ----
        *(float4*)&M1[r*LDP + 4*q] = make_float4(c0, c1, c2, c3);
        __builtin_amdgcn_wave_barrier();
        float cp[4] = {Qq[0], Qq[1], Qq[2], Qq[3]};
        #pragma unroll
        for (int k = 0; k < 16; ++k) {
            float4 ck = *(const float4*)&M1[k*LDP + 4*q];
            cp[0] += Fr[k]*ck.x; cp[1] += Fr[k]*ck.y;
            cp[2] += Fr[k]*ck.z; cp[3] += Fr[k]*ck.w;
        }
        __builtin_amdgcn_wave_barrier();
        // ---- HPT[r][n] = sum_k cov_p[r][k] H[n][k] ----
        float hv[4];
        #pragma unroll
        for (int n = 0; n < 4; ++n) {
            float s = cp[0]*Hn4q[n][0] + cp[1]*Hn4q[n][1]
                    + cp[2]*Hn4q[n][2] + cp[3]*Hn4q[n][3];
            s += __shfl_xor(s, 16);
            s += __shfl_xor(s, 32);
            hv[n] = s;                      // replicated over q
        }
        // ---- S[q][n] = sum_r H[q][r] HPT[r][n] + R ----
        float sm[4];
        #pragma unroll
        for (int n = 0; n < 4; ++n) sm[n] = Hqr * hv[n];
        #pragma unroll
        for (int d = 1; d < 16; d <<= 1) {
            #pragma unroll
            for (int n = 0; n < 4; ++n) sm[n] += __shfl_xor(sm[n], d);
        }
        #pragma unroll
        for (int n = 0; n < 4; ++n) sm[n] += Rrow[n];
        float sf[16];
        #pragma unroll
        for (int j = 0; j < 4; ++j)
            #pragma unroll
            for (int n = 0; n < 4; ++n)
                sf[4*j + n] = __shfl(sm[n], (j << 4) | r);
        // ---- solve S x = HP[:,r]  (x_m = Kt[m][r]) ----
        float b0 = hv[0], b1 = hv[1], b2 = hv[2], b3 = hv[3];
        float a00 = sf[0],  a01 = sf[1],  a02 = sf[2],  a03 = sf[3];
        float a11 = sf[5],  a12 = sf[6],  a13 = sf[7];
        float a22 = sf[10], a23 = sf[11];
        float a33 = sf[15];
        float i0 = 1.0f / a00;
        float g1 = a01*i0, g2 = a02*i0, g3 = a03*i0;
        a11 -= g1*a01; a12 -= g1*a02; a13 -= g1*a03;
        a22 -= g2*a02; a23 -= g2*a03;
        a33 -= g3*a03;
        b1 -= g1*b0; b2 -= g2*b0; b3 -= g3*b0;
        float i1 = 1.0f / a11;
        float h2 = a12*i1, h3 = a13*i1;
        a22 -= h2*a12; a23 -= h2*a13;
        a33 -= h3*a13;
        b2 -= h2*b1; b3 -= h3*b1;
        float i2 = 1.0f / a22;
        float w3 = a23*i2;
        a33 -= w3*a23;
        b3 -= w3*b2;
        float x3 = b3 / a33;
        float x2 = (b2 - a23*x3) * i2;
        float x1 = (b1 - a12*x2 - a13*x3) * i1;
        float x0 = (b0 - a01*x1 - a02*x2 - a03*x3) * i0;
        // ---- A_t[r][4q+i] in registers ----
        float av[4];
        #pragma unroll
        for (int i = 0; i < 4; ++i)
            av[i] = Frq[i] - (x0*HFq[0][i] + x1*HFq[1][i] + x2*HFq[2][i] + x3*HFq[3][i]);

        // ================= means step (this wave's batch), inline ==========
        // nm[r] = sum_c A[r][c] mean[c] + sum_m Kt[m][r] y[m]
        float4 ynext = yv;
        if (t + 1 < TT) ynext = Y4[t + 1];          // prefetch (off-chain)
        float pacc = av[0]*mq[0] + av[1]*mq[1] + av[2]*mq[2] + av[3]*mq[3];
        pacc += __shfl_xor(pacc, 16);
        pacc += __shfl_xor(pacc, 32);               // sum over q-quarters
        float nm = pacc + x0*yv.x + x1*yv.y + x2*yv.z + x3*yv.w;
        if (q == 0) outb[(size_t)t * 16 + r] = nm;  // fire-and-forget
        // redistribute: mean[4q+i] lives at lane 4q+i (q'=0 copy of row 4q+i)
        mq[0] = __shfl(nm, 4*q + 0);
        mq[1] = __shfl(nm, 4*q + 1);
        mq[2] = __shfl(nm, 4*q + 2);
        mq[3] = __shfl(nm, 4*q + 3);
        yv = ynext;

        // ---- cov_u[r][4q+i] = cp[i] - sum_m Kt[m][r] HPT[4q+i][m] ----
        float cu[4];
        #pragma unroll
        for (int i = 0; i < 4; ++i) {
            float h0 = __shfl(hv[0], (l & 48) | (4*q + i));
            float h1 = __shfl(hv[1], (l & 48) | (4*q + i));
            float h2s = __shfl(hv[2], (l & 48) | (4*q + i));
            float h3s = __shfl(hv[3], (l & 48) | (4*q + i));
            cu[i] = cp[i] - (x0*h0 + x1*h1 + x2*h2s + x3*h3s);
        }
        // ---- symmetrize + rebuild replicated row: P = 0.5 (cu + cu^T) ----
        *(float4*)&M2[r*LDP + 4*q] = make_float4(cu[0], cu[1], cu[2], cu[3]);
        #pragma unroll
        for (int i = 0; i < 4; ++i) M1[(4*q + i)*LDP + r] = cu[i];
        __builtin_amdgcn_wave_barrier();
        #pragma unroll
        for (int j = 0; j < 4; ++j) {
            float4 va = *(const float4*)&M2[r*LDP + 4*j];
            float4 vb = *(const float4*)&M1[r*LDP + 4*j];   // = cu^T row r
            prow[4*j+0] = 0.5f*(va.x + vb.x);
            prow[4*j+1] = 0.5f*(va.y + vb.y);
            prow[4*j+2] = 0.5f*(va.z + vb.z);
            prow[4*j+3] = 0.5f*(va.w + vb.w);
        }
        __builtin_amdgcn_wave_barrier();
    }
}

extern "C" void kernel_launch(void* const* d_in, const int* in_sizes, int n_in,
                              void* d_out, int out_size, void* d_ws, size_t ws_size,
                              hipStream_t stream)
{
    const float* y   = (const float*)d_in[0];
    const float* F   = (const float*)d_in[1];
    const float* H   = (const float*)d_in[2];
    const float* Qc  = (const float*)d_in[3];
    const float* Rc  = (const float*)d_in[4];
    const float* im  = (const float*)d_in[5];
    const float* icc = (const float*)d_in[6];
    float* out = (float*)d_out;

    ssm_wave<<<dim3(BB / WPB), dim3(64 * WPB), 0, stream>>>(y, F, H, Qc, Rc, im, icc, out);
}

// Round 9
// 691.263 us; speedup vs baseline: 2.9271x; 2.9271x over previous
//
#include <hip/hip_runtime.h>

#define TT 1024
#define BB 2048
#define EPSC 1e-4f
#define LDP 20      // padded LDS row stride (floats): max 2-way bank aliasing (free)
#define W 32        // consumer burst window (steps)
#define DELTA 2e-6f // Riccati convergence threshold (P-scale ~0.05 -> rel ~4e-5)

// Fused Kalman filter, R4 lockstep structure + consumer burst-buffering +
// Riccati steady-state cutoff. 256 blocks x 192 threads (3 waves, 1 block/CU).
// wave 0: batch-independent Riccati/gain chain -> A_t/G_t in LDS double buffer.
//         When P converges (time-invariant model => geometric convergence),
//         writes steady A/G into BOTH buffers and idles.
// waves 1-2: 4 batches each, one step behind. Global y-loads/out-stores only
//         once per 32-step window (LDS ybuf/obuf), so the per-step
//         __syncthreads never drains global traffic.
__global__ __launch_bounds__(192, 1)
void ssm_fused(const float* __restrict__ y, const float* __restrict__ F,
               const float* __restrict__ H, const float* __restrict__ Qc,
               const float* __restrict__ Rc, const float* __restrict__ im,
               const float* __restrict__ icc, float* __restrict__ out)
{
    __shared__ __align__(16) float m1[16 * LDP];        // transpose scratch
    __shared__ __align__(16) float m2[16 * LDP];        // symmetrize scratch
    __shared__ __align__(16) float A_l[2][16 * LDP];    // A_t double buffer
    __shared__ __align__(16) float G_l[2][64];          // G_t double buffer
    __shared__ __align__(16) float ybuf[2][4][W][4];    // per-consumer-wave y window
    __shared__ __align__(16) float obuf[2][4][W][16];   // per-consumer-wave out window

    const int tid = (int)threadIdx.x;
    const int wv  = tid >> 6;
    const int l   = tid & 63;
    const int r   = l & 15;
    const int q   = l >> 4;

    // ---- producer loop-invariant registers ----
    float Fq[4][16];   // F[4q+i][k]
    float Fr[16];      // F[r][k]
    float Frq[4];      // F[r][4q+i]
    float HFq[4][4];   // (H F)[m][4q+i]
    float Hn4q[4][4];  // H[n][4q+i]
    float Qq[4];       // Q[r][4q+i]
    float Rrow[4];     // R[q][n]
    float Hqr = 0.0f;  // H[q][r]
    float prow[16];    // replicated full row r of symmetric P

    // ---- consumer registers ----
    float mean[16];
    const float4* Y4 = nullptr;   // base of this wave's 4 batches
    size_t outbase = 0;

    if (wv == 0) {
        Hqr = H[q*16 + r];
        #pragma unroll
        for (int i = 0; i < 4; ++i)
            #pragma unroll
            for (int k = 0; k < 16; ++k) Fq[i][k] = F[(4*q + i)*16 + k];
        #pragma unroll
        for (int k = 0; k < 16; ++k) Fr[k] = F[r*16 + k];
        #pragma unroll
        for (int i = 0; i < 4; ++i) Frq[i] = F[r*16 + 4*q + i];
        #pragma unroll
        for (int n = 0; n < 4; ++n)
            #pragma unroll
            for (int i = 0; i < 4; ++i) Hn4q[n][i] = H[n*16 + 4*q + i];
        #pragma unroll
        for (int m = 0; m < 4; ++m)
            #pragma unroll
            for (int i = 0; i < 4; ++i) {
                float acc = 0.0f;
                #pragma unroll
                for (int k = 0; k < 16; ++k) acc += H[m*16 + k] * F[k*16 + 4*q + i];
                HFq[m][i] = acc;
            }
        #pragma unroll
        for (int i = 0; i < 4; ++i) {
            const int c = 4*q + i;
            float acc = (r == c) ? EPSC : 0.0f;
            #pragma unroll
            for (int k = 0; k < 16; ++k) acc += Qc[r*16 + k] * Qc[c*16 + k];
            Qq[i] = acc;
        }
        #pragma unroll
        for (int n = 0; n < 4; ++n) {
            float acc = (q == n) ? EPSC : 0.0f;
            #pragma unroll
            for (int k = 0; k < 4; ++k) acc += Rc[q*4 + k] * Rc[n*4 + k];
            Rrow[n] = acc;
        }
        #pragma unroll
        for (int k = 0; k < 16; ++k) {
            float acc = (r == k) ? EPSC : 0.0f;
            #pragma unroll
            for (int j = 0; j < 16; ++j) acc += icc[r*16 + j] * icc[k*16 + j];
            prow[k] = acc;   // P0 row r (exactly symmetric by construction)
        }
    } else {
        const int widx = wv - 1;
        const int b0 = (int)blockIdx.x * 8 + widx * 4;
        #pragma unroll
        for (int k = 0; k < 16; ++k) mean[k] = im[k];
        Y4 = (const float4*)y + (size_t)b0 * TT;
        outbase = ((size_t)b0 + q) * TT * 16;   // this thread's batch
    }

    bool conv = false;
    #pragma unroll 1
    for (int t = 0; t <= TT; ++t) {
        if (wv == 0) {
            if (t < TT && !conv) {
                // ================= gains step t (wave-synchronous) =========
                // C = P F^T
                float c0 = 0.f, c1 = 0.f, c2 = 0.f, c3 = 0.f;
                #pragma unroll
                for (int k = 0; k < 16; ++k) {
                    c0 += prow[k]*Fq[0][k]; c1 += prow[k]*Fq[1][k];
                    c2 += prow[k]*Fq[2][k]; c3 += prow[k]*Fq[3][k];
                }
                // RT_A: transpose C through LDS; cov_p = F C + Q
                *(float4*)&m1[r*LDP + 4*q] = make_float4(c0, c1, c2, c3);
                __builtin_amdgcn_wave_barrier();
                float cp[4] = {Qq[0], Qq[1], Qq[2], Qq[3]};
                #pragma unroll
                for (int k = 0; k < 16; ++k) {
                    float4 ck = *(const float4*)&m1[k*LDP + 4*q];
                    cp[0] += Fr[k]*ck.x; cp[1] += Fr[k]*ck.y;
                    cp[2] += Fr[k]*ck.z; cp[3] += Fr[k]*ck.w;
                }
                __builtin_amdgcn_wave_barrier();
                // HPT[r][n] = sum_k cov_p[r][k] H[n][k]
                float hv[4];
                #pragma unroll
                for (int n = 0; n < 4; ++n) {
                    float s = cp[0]*Hn4q[n][0] + cp[1]*Hn4q[n][1]
                            + cp[2]*Hn4q[n][2] + cp[3]*Hn4q[n][3];
                    s += __shfl_xor(s, 16);
                    s += __shfl_xor(s, 32);
                    hv[n] = s;
                }
                // S[q][n] = sum_r H[q][r] HPT[r][n] + R
                float sm[4];
                #pragma unroll
                for (int n = 0; n < 4; ++n) sm[n] = Hqr * hv[n];
                #pragma unroll
                for (int d = 1; d < 16; d <<= 1) {
                    #pragma unroll
                    for (int n = 0; n < 4; ++n) sm[n] += __shfl_xor(sm[n], d);
                }
                #pragma unroll
                for (int n = 0; n < 4; ++n) sm[n] += Rrow[n];
                float sf[16];
                #pragma unroll
                for (int j = 0; j < 4; ++j)
                    #pragma unroll
                    for (int n = 0; n < 4; ++n)
                        sf[4*j + n] = __shfl(sm[n], (j << 4) | r);
                // solve S x = HP[:,r]
                float b0 = hv[0], b1 = hv[1], b2 = hv[2], b3 = hv[3];
                float a00 = sf[0],  a01 = sf[1],  a02 = sf[2],  a03 = sf[3];
                float a11 = sf[5],  a12 = sf[6],  a13 = sf[7];
                float a22 = sf[10], a23 = sf[11];
                float a33 = sf[15];
                float i0 = 1.0f / a00;
                float g1 = a01*i0, g2 = a02*i0, g3 = a03*i0;
                a11 -= g1*a01; a12 -= g1*a02; a13 -= g1*a03;
                a22 -= g2*a02; a23 -= g2*a03;
                a33 -= g3*a03;
                b1 -= g1*b0; b2 -= g2*b0; b3 -= g3*b0;
                float i1 = 1.0f / a11;
                float h2 = a12*i1, h3 = a13*i1;
                a22 -= h2*a12; a23 -= h2*a13;
                a33 -= h3*a13;
                b2 -= h2*b1; b3 -= h3*b1;
                float i2 = 1.0f / a22;
                float w3 = a23*i2;
                a33 -= w3*a23;
                b3 -= w3*b2;
                float x3 = b3 / a33;
                float x2 = (b2 - a23*x3) * i2;
                float x1 = (b1 - a12*x2 - a13*x3) * i1;
                float x0 = (b0 - a01*x1 - a02*x2 - a03*x3) * i0;
                // A_t row -> LDS double buffer
                const int buf = t & 1;
                float av[4];
                #pragma unroll
                for (int i = 0; i < 4; ++i)
                    av[i] = Frq[i] - (x0*HFq[0][i] + x1*HFq[1][i] + x2*HFq[2][i] + x3*HFq[3][i]);
                *(float4*)&A_l[buf][r*LDP + 4*q] = make_float4(av[0], av[1], av[2], av[3]);
                if (q == 0)
                    *(float4*)&G_l[buf][r*4] = make_float4(x0, x1, x2, x3);
                // cov_u
                float cu[4];
                #pragma unroll
                for (int i = 0; i < 4; ++i) {
                    float h0 = __shfl(hv[0], (l & 48) | (4*q + i));
                    float h1 = __shfl(hv[1], (l & 48) | (4*q + i));
                    float h2s = __shfl(hv[2], (l & 48) | (4*q + i));
                    float h3s = __shfl(hv[3], (l & 48) | (4*q + i));
                    cu[i] = cp[i] - (x0*h0 + x1*h1 + x2*h2s + x3*h3s);
                }
                // convergence check (time-invariant model => P -> P_inf)
                float md = fmaxf(fmaxf(fabsf(cu[0] - prow[4*q+0]),
                                       fabsf(cu[1] - prow[4*q+1])),
                                 fmaxf(fabsf(cu[2] - prow[4*q+2]),
                                       fabsf(cu[3] - prow[4*q+3])));
                if (t > 2 && __all(md <= DELTA)) {
                    // steady state: fill the OTHER buffer too, then idle
                    const int ob = 1 - buf;
                    *(float4*)&A_l[ob][r*LDP + 4*q] = make_float4(av[0], av[1], av[2], av[3]);
                    if (q == 0)
                        *(float4*)&G_l[ob][r*4] = make_float4(x0, x1, x2, x3);
                    conv = true;
                } else {
                    // RT_B: symmetrize + rebuild replicated row
                    *(float4*)&m2[r*LDP + 4*q] = make_float4(cu[0], cu[1], cu[2], cu[3]);
                    #pragma unroll
                    for (int i = 0; i < 4; ++i) m1[(4*q + i)*LDP + r] = cu[i];
                    __builtin_amdgcn_wave_barrier();
                    #pragma unroll
                    for (int j = 0; j < 4; ++j) {
                        float4 va = *(const float4*)&m2[r*LDP + 4*j];
                        float4 vb = *(const float4*)&m1[r*LDP + 4*j];
                        prow[4*j+0] = 0.5f*(va.x + vb.x);
                        prow[4*j+1] = 0.5f*(va.y + vb.y);
                        prow[4*j+2] = 0.5f*(va.z + vb.z);
                        prow[4*j+3] = 0.5f*(va.w + vb.w);
                    }
                    __builtin_amdgcn_wave_barrier();
                }
            }
        } else if (t > 0) {
            // ================= consumers: step u = t-1, 4 batches/wave =====
            const int u    = t - 1;
            const int widx = wv - 1;
            if ((u & (W - 1)) == 0) {
                // flush previous out-window (global stores, drain amortized)
                if (u > 0) {
                    const int base = u - W;
                    #pragma unroll
                    for (int k = 0; k < 8; ++k) {
                        const int idx = r + (k << 4);           // 0..127
                        const int s = idx >> 2, c4 = idx & 3;
                        float4 v = *(const float4*)&obuf[widx][q][s][c4*4];
                        *(float4*)&out[outbase + (size_t)(base + s)*16 + c4*4] = v;
                    }
                }
                // load this window's y into LDS
                #pragma unroll
                for (int k = 0; k < 2; ++k) {
                    const int idx = l + (k << 6);               // 0..127
                    const int bi = idx >> 5, s = idx & 31;
                    float4 v = Y4[(size_t)bi * TT + u + s];
                    *(float4*)&ybuf[widx][bi][s][0] = v;
                }
                __builtin_amdgcn_wave_barrier();
            }
            const int slot = u & 1;
            const int ws   = u & (W - 1);
            float4 yv = *(const float4*)&ybuf[widx][q][ws][0];
            float4 gt = *(const float4*)&G_l[slot][r*4];
            float4 a0 = *(const float4*)&A_l[slot][r*LDP + 0];
            float4 a1 = *(const float4*)&A_l[slot][r*LDP + 4];
            float4 a2 = *(const float4*)&A_l[slot][r*LDP + 8];
            float4 a3 = *(const float4*)&A_l[slot][r*LDP + 12];
            float nm = a0.x*mean[0]  + a0.y*mean[1]  + a0.z*mean[2]  + a0.w*mean[3]
                     + a1.x*mean[4]  + a1.y*mean[5]  + a1.z*mean[6]  + a1.w*mean[7]
                     + a2.x*mean[8]  + a2.y*mean[9]  + a2.z*mean[10] + a2.w*mean[11]
                     + a3.x*mean[12] + a3.y*mean[13] + a3.z*mean[14] + a3.w*mean[15]
                     + gt.x*yv.x + gt.y*yv.y + gt.z*yv.z + gt.w*yv.w;
            obuf[widx][q][ws][r] = nm;
            // redistribute mean within the 16-lane group via shuffles
            #pragma unroll
            for (int j = 0; j < 16; ++j)
                mean[j] = __shfl(nm, (l & 48) | j);
        }
        __syncthreads();
    }
    // final flush: last window (steps TT-W .. TT-1)
    if (wv > 0) {
        const int widx = wv - 1;
        #pragma unroll
        for (int k = 0; k < 8; ++k) {
            const int idx = r + (k << 4);
            const int s = idx >> 2, c4 = idx & 3;
            float4 v = *(const float4*)&obuf[widx][q][s][c4*4];
            *(float4*)&out[outbase + (size_t)(TT - W + s)*16 + c4*4] = v;
        }
    }
}

extern "C" void kernel_launch(void* const* d_in, const int* in_sizes, int n_in,
                              void* d_out, int out_size, void* d_ws, size_t ws_size,
                              hipStream_t stream)
{
    const float* y   = (const float*)d_in[0];
    const float* F   = (const float*)d_in[1];
    const float* H   = (const float*)d_in[2];
    const float* Qc  = (const float*)d_in[3];
    const float* Rc  = (const float*)d_in[4];
    const float* im  = (const float*)d_in[5];
    const float* icc = (const float*)d_in[6];
    float* out = (float*)d_out;

    ssm_fused<<<dim3(BB/8), dim3(192), 0, stream>>>(y, F, H, Qc, Rc, im, icc, out);
}